// Round 2
// baseline (1106.710 us; speedup 1.0000x reference)
//
#include <hip/hip_runtime.h>
#include <math.h>

#define B_ 16
#define C_ 256
#define H_ 64
#define W_ 64
#define N_ 8
#define D_ 32
#define M_ (B_*H_*W_)              // 65536 rows
#define SCALING 0.17677669529663687f

// Workspace plan (3 x 64MB buffers + tables = 193.1 MB):
//   B1: qr -> y -> t2        B2: kr -> f        B3: v -> v5 -> attn_out -> xt -> (t2 src for final)
//   d_out: lepe -> t1 -> final output
// Attention writes in-place (each block stages its V region in LDS first and
// only ever writes its own region).

// ---------------------------------------------------------------- tables ----
__global__ __launch_bounds__(256) void k_tables(float* __restrict__ sint,
                                                float* __restrict__ cost,
                                                float* __restrict__ maskt)
{
    int t = blockIdx.x * 256 + threadIdx.x;   // 131072 = 4096*32
    int p = t >> 5, d = t & 31;
    int j = d >> 1;
    float ang = (float)pow(10000.0, -(double)j / 15.0);  // linspace(0,1,16)[j]=j/15
    float arg = (float)p * ang;
    sint[t] = sinf(arg);
    cost[t] = cosf(arg);
    if (t < N_*64*64) {
        int n = t >> 12;
        int q = (t >> 6) & 63, k = t & 63;
        int ad = (q > k) ? (q - k) : (k - q);
        double decay = log(1.0 - exp2(-1.0 - 3.0 * (double)n / 8.0));
        maskt[t] = (float)((double)ad * decay);
    }
}

// ------------------------------------------------------------- transpose ----
// dst[c][r] = src[r][c] per batch (blockIdx.z). rows/cols of src.
__global__ __launch_bounds__(256) void k_transpose(const float* __restrict__ src,
                                                   float* __restrict__ dst,
                                                   int rows, int cols)
{
    __shared__ float t[32][33];
    int tx = threadIdx.x & 31, ty = threadIdx.x >> 5;   // 32 x 8
    int bx = blockIdx.x * 32, by = blockIdx.y * 32;     // bx: col base, by: row base
    size_t bo = (size_t)blockIdx.z * rows * cols;
    #pragma unroll
    for (int j = 0; j < 4; ++j)
        t[ty + j*8][tx] = src[bo + (size_t)(by + ty + j*8) * cols + bx + tx];
    __syncthreads();
    #pragma unroll
    for (int j = 0; j < 4; ++j)
        dst[bo + (size_t)(bx + ty + j*8) * rows + by + tx] = t[tx][ty + j*8];
}

// ------------------------------------------------------------- QKV GEMM -----
// Reads x in (B,C,H,W) directly: a 64-row tile == one (b,h) line, w=0..63.
// z = blockIdx.z selects q/k/v. Epilogue: bias, k-scaling, theta shift,
// writes to (b,n,h,w,d) layout.
__global__ __launch_bounds__(256) void k_gemm_qkv(
    const float* __restrict__ x,
    const float* __restrict__ Wq, const float* __restrict__ bq,
    const float* __restrict__ Wk, const float* __restrict__ bk,
    const float* __restrict__ Wv, const float* __restrict__ bv,
    float* __restrict__ qro, float* __restrict__ kro, float* __restrict__ vo,
    const float* __restrict__ sint, const float* __restrict__ cost)
{
    __shared__ float As[16*68];
    __shared__ float Bs[16*68];
    int z = blockIdx.z;
    const float* Wm   = (z==0) ? Wq : (z==1) ? Wk : Wv;
    const float* bias = (z==0) ? bq : (z==1) ? bk : bv;
    float* dst        = (z==0) ? qro : (z==1) ? kro : vo;

    int tid = threadIdx.x;
    int tx = tid & 15, ty = tid >> 4;
    int r0 = blockIdx.x * 64;
    int c0 = blockIdx.y * 64;
    int bb = r0 >> 12;
    int hh = (r0 >> 6) & 63;

    int l_k  = tid >> 4;            // 0..15
    int l_w4 = (tid & 15) * 4;      // 0..60
    const float* xbase = x + (size_t)bb * 256 * 4096 + hh * 64;

    float acc[4][4] = {};
    for (int kt = 0; kt < 256; kt += 16) {
        __syncthreads();
        *(float4*)(As + l_k*68 + l_w4) =
            *(const float4*)(xbase + (size_t)(kt + l_k) * 4096 + l_w4);
        *(float4*)(Bs + l_k*68 + l_w4) =
            *(const float4*)(Wm + (size_t)(kt + l_k) * 256 + c0 + l_w4);
        __syncthreads();
        #pragma unroll
        for (int kk = 0; kk < 16; ++kk) {
            const float4 av = *(const float4*)(As + kk*68 + ty*4);
            const float4 bw = *(const float4*)(Bs + kk*68 + tx*4);
            const float a0=av.x, a1=av.y, a2=av.z, a3=av.w;
            const float w0=bw.x, w1=bw.y, w2=bw.z, w3=bw.w;
            acc[0][0]=fmaf(a0,w0,acc[0][0]); acc[0][1]=fmaf(a0,w1,acc[0][1]);
            acc[0][2]=fmaf(a0,w2,acc[0][2]); acc[0][3]=fmaf(a0,w3,acc[0][3]);
            acc[1][0]=fmaf(a1,w0,acc[1][0]); acc[1][1]=fmaf(a1,w1,acc[1][1]);
            acc[1][2]=fmaf(a1,w2,acc[1][2]); acc[1][3]=fmaf(a1,w3,acc[1][3]);
            acc[2][0]=fmaf(a2,w0,acc[2][0]); acc[2][1]=fmaf(a2,w1,acc[2][1]);
            acc[2][2]=fmaf(a2,w2,acc[2][2]); acc[2][3]=fmaf(a2,w3,acc[2][3]);
            acc[3][0]=fmaf(a3,w0,acc[3][0]); acc[3][1]=fmaf(a3,w1,acc[3][1]);
            acc[3][2]=fmaf(a3,w2,acc[3][2]); acc[3][3]=fmaf(a3,w3,acc[3][3]);
        }
    }

    int cb  = c0 + tx*4;
    int n   = cb >> 5;
    int dlo = cb & 31;
    float4 bias4 = *(const float4*)(bias + cb);
    #pragma unroll
    for (int i = 0; i < 4; ++i) {
        int w   = ty*4 + i;
        int pos = hh*64 + w;
        float v0 = acc[i][0] + bias4.x;
        float v1 = acc[i][1] + bias4.y;
        float v2 = acc[i][2] + bias4.z;
        float v3 = acc[i][3] + bias4.w;
        if (z == 1) { v0*=SCALING; v1*=SCALING; v2*=SCALING; v3*=SCALING; }
        if (z < 2) { // theta shift on pairs (dlo,dlo+1),(dlo+2,dlo+3)
            float4 s4 = *(const float4*)(sint + pos*32 + dlo);
            float4 c4 = *(const float4*)(cost + pos*32 + dlo);
            float e0 = v0*c4.x - v1*s4.x;
            float o0 = v1*c4.y + v0*s4.y;
            float e1 = v2*c4.z - v3*s4.z;
            float o1 = v3*c4.w + v2*s4.w;
            v0=e0; v1=o0; v2=e1; v3=o1;
        }
        float* p = dst + (size_t)(((bb*8 + n)*64 + hh)*64 + w) * 32 + dlo;
        *(float4*)p = make_float4(v0, v1, v2, v3);
    }
}

// ------------------------------------------------------------ plain GEMM ----
// out[r][c] = A[r][:] @ Wm[:,c] + bias[c]   (A in (M,256) row-major)
__global__ __launch_bounds__(256) void k_gemm_plain(
    const float* __restrict__ A,
    const float* __restrict__ Wm, const float* __restrict__ bias,
    float* __restrict__ out)
{
    __shared__ float As[16*68];
    __shared__ float Bs[16*68];
    int tid = threadIdx.x;
    int tx = tid & 15, ty = tid >> 4;
    int r0 = blockIdx.x * 64;
    int c0 = blockIdx.y * 64;
    int la_r = tid >> 2;
    int la_k = (tid & 3) * 4;
    int lb_k = tid >> 4, lb_c = (tid & 15) * 4;

    float acc[4][4] = {};
    for (int kt = 0; kt < 256; kt += 16) {
        __syncthreads();
        float4 a4 = *(const float4*)(A + (size_t)(r0 + la_r)*256 + kt + la_k);
        As[(la_k+0)*68 + la_r] = a4.x;
        As[(la_k+1)*68 + la_r] = a4.y;
        As[(la_k+2)*68 + la_r] = a4.z;
        As[(la_k+3)*68 + la_r] = a4.w;
        *(float4*)(Bs + lb_k*68 + lb_c) =
            *(const float4*)(Wm + (size_t)(kt + lb_k)*256 + c0 + lb_c);
        __syncthreads();
        #pragma unroll
        for (int kk = 0; kk < 16; ++kk) {
            const float4 av = *(const float4*)(As + kk*68 + ty*4);
            const float4 bw = *(const float4*)(Bs + kk*68 + tx*4);
            const float a0=av.x, a1=av.y, a2=av.z, a3=av.w;
            const float w0=bw.x, w1=bw.y, w2=bw.z, w3=bw.w;
            acc[0][0]=fmaf(a0,w0,acc[0][0]); acc[0][1]=fmaf(a0,w1,acc[0][1]);
            acc[0][2]=fmaf(a0,w2,acc[0][2]); acc[0][3]=fmaf(a0,w3,acc[0][3]);
            acc[1][0]=fmaf(a1,w0,acc[1][0]); acc[1][1]=fmaf(a1,w1,acc[1][1]);
            acc[1][2]=fmaf(a1,w2,acc[1][2]); acc[1][3]=fmaf(a1,w3,acc[1][3]);
            acc[2][0]=fmaf(a2,w0,acc[2][0]); acc[2][1]=fmaf(a2,w1,acc[2][1]);
            acc[2][2]=fmaf(a2,w2,acc[2][2]); acc[2][3]=fmaf(a2,w3,acc[2][3]);
            acc[3][0]=fmaf(a3,w0,acc[3][0]); acc[3][1]=fmaf(a3,w1,acc[3][1]);
            acc[3][2]=fmaf(a3,w2,acc[3][2]); acc[3][3]=fmaf(a3,w3,acc[3][3]);
        }
    }
    float4 bias4 = *(const float4*)(bias + c0 + tx*4);
    #pragma unroll
    for (int i = 0; i < 4; ++i) {
        float4 o4 = make_float4(acc[i][0]+bias4.x, acc[i][1]+bias4.y,
                                acc[i][2]+bias4.z, acc[i][3]+bias4.w);
        *(float4*)(out + (size_t)(r0 + ty*4 + i)*256 + c0 + tx*4) = o4;
    }
}

// ------------------------------------------------------- Wo GEMM (y) --------
// A is attn_out stored in (b,n,h,w,d) layout: logical row r=(b,h,w), col
// c=n*32+dl at addr (b*8+n)*131072 + h*2048 + w*32 + dl. A2 = lepe, (M,256)
// row-major. out = (A+A2)@Wo + bo, (M,256) row-major.
__global__ __launch_bounds__(256) void k_gemm_y(
    const float* __restrict__ Av5, const float* __restrict__ A2,
    const float* __restrict__ Wm, const float* __restrict__ bias,
    float* __restrict__ out)
{
    __shared__ float As[16*68];
    __shared__ float Bs[16*68];
    int tid = threadIdx.x;
    int tx = tid & 15, ty = tid >> 4;
    int r0 = blockIdx.x * 64;
    int c0 = blockIdx.y * 64;
    int la_r = tid >> 2;
    int la_k = (tid & 3) * 4;
    int lb_k = tid >> 4, lb_c = (tid & 15) * 4;

    int r  = r0 + la_r;
    int bb = r >> 12, hh = (r >> 6) & 63, ww = r & 63;
    size_t abase = (size_t)bb * 1048576 + (size_t)hh * 2048 + ww * 32;

    float acc[4][4] = {};
    for (int kt = 0; kt < 256; kt += 16) {
        int kc = kt + la_k;
        int nn = kc >> 5, dl = kc & 31;
        __syncthreads();
        float4 a4 = *(const float4*)(Av5 + abase + (size_t)nn * 131072 + dl);
        float4 l4 = *(const float4*)(A2 + (size_t)r * 256 + kc);
        a4.x += l4.x; a4.y += l4.y; a4.z += l4.z; a4.w += l4.w;
        As[(la_k+0)*68 + la_r] = a4.x;
        As[(la_k+1)*68 + la_r] = a4.y;
        As[(la_k+2)*68 + la_r] = a4.z;
        As[(la_k+3)*68 + la_r] = a4.w;
        *(float4*)(Bs + lb_k*68 + lb_c) =
            *(const float4*)(Wm + (size_t)(kt + lb_k)*256 + c0 + lb_c);
        __syncthreads();
        #pragma unroll
        for (int kk = 0; kk < 16; ++kk) {
            const float4 av = *(const float4*)(As + kk*68 + ty*4);
            const float4 bw = *(const float4*)(Bs + kk*68 + tx*4);
            const float a0=av.x, a1=av.y, a2=av.z, a3=av.w;
            const float w0=bw.x, w1=bw.y, w2=bw.z, w3=bw.w;
            acc[0][0]=fmaf(a0,w0,acc[0][0]); acc[0][1]=fmaf(a0,w1,acc[0][1]);
            acc[0][2]=fmaf(a0,w2,acc[0][2]); acc[0][3]=fmaf(a0,w3,acc[0][3]);
            acc[1][0]=fmaf(a1,w0,acc[1][0]); acc[1][1]=fmaf(a1,w1,acc[1][1]);
            acc[1][2]=fmaf(a1,w2,acc[1][2]); acc[1][3]=fmaf(a1,w3,acc[1][3]);
            acc[2][0]=fmaf(a2,w0,acc[2][0]); acc[2][1]=fmaf(a2,w1,acc[2][1]);
            acc[2][2]=fmaf(a2,w2,acc[2][2]); acc[2][3]=fmaf(a2,w3,acc[2][3]);
            acc[3][0]=fmaf(a3,w0,acc[3][0]); acc[3][1]=fmaf(a3,w1,acc[3][1]);
            acc[3][2]=fmaf(a3,w2,acc[3][2]); acc[3][3]=fmaf(a3,w3,acc[3][3]);
        }
    }
    float4 bias4 = *(const float4*)(bias + c0 + tx*4);
    #pragma unroll
    for (int i = 0; i < 4; ++i) {
        float4 o4 = make_float4(acc[i][0]+bias4.x, acc[i][1]+bias4.y,
                                acc[i][2]+bias4.z, acc[i][3]+bias4.w);
        *(float4*)(out + (size_t)(r0 + ty*4 + i)*256 + c0 + tx*4) = o4;
    }
}

// -------------------------------------------------------------- LePE conv ---
// depthwise 5x5, pad 2. v in (b,n,h,w,d); out in (b,h,w,c), c=n*32+d.
__global__ __launch_bounds__(256) void k_conv(
    const float* __restrict__ v, const float* __restrict__ cw,
    const float* __restrict__ cb, float* __restrict__ out)
{
    __shared__ float vs[5*68*36];   // (rr*68+col)*36 + d, col = w+2 (0..67)
    __shared__ float wts[25*32];
    int h = blockIdx.x, n = blockIdx.y, b = blockIdx.z;
    int tid = threadIdx.x;
    for (int i = tid; i < 5*68*36; i += 256) vs[i] = 0.f;
    for (int i = tid; i < 800; i += 256) {
        int tap = i >> 5, d = i & 31;
        wts[i] = cw[tap*256 + n*32 + d];
    }
    __syncthreads();
    const float* vb = v + (size_t)((b*8 + n)*64) * 2048;
    #pragma unroll
    for (int it = 0; it < 10; ++it) {
        int f  = tid + it*256;        // 0..2559 : 5 rows x 512 float4
        int rr = f >> 9;
        int f2 = f & 511;
        int w  = f2 >> 3, d4 = (f2 & 7) * 4;
        int hh = h + rr - 2;
        if (hh >= 0 && hh < 64)
            *(float4*)(vs + (rr*68 + w + 2)*36 + d4) =
                *(const float4*)(vb + hh*2048 + w*32 + d4);
    }
    __syncthreads();
    int d = tid & 31, wq = tid >> 5;
    float wreg[25];
    #pragma unroll
    for (int t5 = 0; t5 < 25; ++t5) wreg[t5] = wts[t5*32 + d];
    float bias = cb[n*32 + d];
    for (int w = wq; w < 64; w += 8) {
        float acc = bias;
        #pragma unroll
        for (int dy = 0; dy < 5; ++dy)
            #pragma unroll
            for (int dx = 0; dx < 5; ++dx)
                acc = fmaf(vs[(dy*68 + w + dx)*36 + d], wreg[dy*5+dx], acc);
        out[(size_t)((b*64 + h)*64 + w)*256 + n*32 + d] = acc;
    }
}

// -------------------------------------------------------------- attention ---
// dir 0: group gid=(b,n,h), seq over w, elem addr = gid*2048 + s*32 + d.
// dir 1: group gid=(b,n,w), seq over h, elem addr = (gid>>6)*131072 + s*2048
//        + (gid&63)*32 + d.
// Output written IN-PLACE over this block's own V region (V fully staged in
// LDS before any write; no other block touches this region). Vb/Ob alias, so
// no __restrict__ on them.
__global__ __launch_bounds__(256) void k_attn(
    const float* __restrict__ Qb, const float* __restrict__ Kb,
    const float* Vb, const float* __restrict__ maskt,
    float* Ob, int dir)
{
    __shared__ float Qs[64*36];
    __shared__ float Ks[64*36];
    __shared__ float Vs[64*36];
    __shared__ float Ps[64*68];
    int gid = blockIdx.x;
    int tid = threadIdx.x;
    int n = (gid >> 6) & 7;
    int base, sstr;
    if (dir == 0) { base = gid * 2048;                              sstr = 32;   }
    else          { base = (gid >> 6) * 131072 + (gid & 63) * 32;   sstr = 2048; }

    #pragma unroll
    for (int it = 0; it < 2; ++it) {
        int f  = tid + it*256;       // 0..511 float4 chunks
        int s  = f >> 3;
        int d4 = (f & 7) * 4;
        int ga = base + s*sstr + d4;
        int la = s*36 + d4;
        *(float4*)(Qs + la) = *(const float4*)(Qb + ga);
        *(float4*)(Ks + la) = *(const float4*)(Kb + ga);
        *(float4*)(Vs + la) = *(const float4*)(Vb + ga);
    }
    __syncthreads();

    int q = tid >> 2, kl = tid & 3;
    float4 qreg[8];
    #pragma unroll
    for (int j = 0; j < 8; ++j) qreg[j] = *(const float4*)(Qs + q*36 + j*4);
    float sv[16];
    const float* mrow = maskt + n*4096 + q*64;
    #pragma unroll
    for (int i = 0; i < 16; ++i) {
        int k = kl + i*4;
        const float4* krow = (const float4*)(Ks + k*36);
        float s = 0.f;
        #pragma unroll
        for (int j = 0; j < 8; ++j) {
            float4 kv = krow[j];
            s = fmaf(qreg[j].x, kv.x, s);
            s = fmaf(qreg[j].y, kv.y, s);
            s = fmaf(qreg[j].z, kv.z, s);
            s = fmaf(qreg[j].w, kv.w, s);
        }
        sv[i] = s + mrow[k];
    }
    float m = sv[0];
    #pragma unroll
    for (int i = 1; i < 16; ++i) m = fmaxf(m, sv[i]);
    m = fmaxf(m, __shfl_xor(m, 1, 4));
    m = fmaxf(m, __shfl_xor(m, 2, 4));
    float sum = 0.f;
    #pragma unroll
    for (int i = 0; i < 16; ++i) { sv[i] = __expf(sv[i] - m); sum += sv[i]; }
    sum += __shfl_xor(sum, 1, 4);
    sum += __shfl_xor(sum, 2, 4);
    float rinv = 1.f / sum;
    #pragma unroll
    for (int i = 0; i < 16; ++i) Ps[q*68 + kl + i*4] = sv[i] * rinv;
    __syncthreads();

    int d0 = (tid & 3) * 8;
    float o[8] = {0,0,0,0,0,0,0,0};
    for (int k = 0; k < 64; ++k) {
        float p = Ps[q*68 + k];
        float4 va  = *(const float4*)(Vs + k*36 + d0);
        float4 vb2 = *(const float4*)(Vs + k*36 + d0 + 4);
        o[0]=fmaf(p,va.x,o[0]);  o[1]=fmaf(p,va.y,o[1]);
        o[2]=fmaf(p,va.z,o[2]);  o[3]=fmaf(p,va.w,o[3]);
        o[4]=fmaf(p,vb2.x,o[4]); o[5]=fmaf(p,vb2.y,o[5]);
        o[6]=fmaf(p,vb2.z,o[6]); o[7]=fmaf(p,vb2.w,o[7]);
    }
    float4 oa = make_float4(o[0],o[1],o[2],o[3]);
    float4 ob = make_float4(o[4],o[5],o[6],o[7]);
    // write query q's output back over this block's own V element (q, d0..)
    float* p = Ob + base + q*sstr + d0;
    *(float4*)p = oa; *(float4*)(p+4) = ob;
}

// ---------------------------------------------------------------- LN(a+b) ---
__global__ __launch_bounds__(256) void k_ln(
    const float* __restrict__ A, const float* __restrict__ Bv,
    const float* __restrict__ g, const float* __restrict__ bb,
    float* __restrict__ out)
{
    int row  = blockIdx.x * 4 + (threadIdx.x >> 6);
    int lane = threadIdx.x & 63;
    size_t off = (size_t)row * 256 + lane*4;
    float4 a4 = *(const float4*)(A + off);
    float4 b4 = *(const float4*)(Bv + off);
    float v0=a4.x+b4.x, v1=a4.y+b4.y, v2=a4.z+b4.z, v3=a4.w+b4.w;
    float s = v0+v1+v2+v3;
    #pragma unroll
    for (int mm = 1; mm < 64; mm <<= 1) s += __shfl_xor(s, mm, 64);
    float mean = s * (1.0f/256.0f);
    float d0=v0-mean, d1=v1-mean, d2=v2-mean, d3=v3-mean;
    float qq = d0*d0 + d1*d1 + d2*d2 + d3*d3;
    #pragma unroll
    for (int mm = 1; mm < 64; mm <<= 1) qq += __shfl_xor(qq, mm, 64);
    float rstd = rsqrtf(qq * (1.0f/256.0f) + 1e-6f);
    float4 g4  = *(const float4*)(g + lane*4);
    float4 be4 = *(const float4*)(bb + lane*4);
    float4 o4 = make_float4(g4.x*d0*rstd + be4.x, g4.y*d1*rstd + be4.y,
                            g4.z*d2*rstd + be4.z, g4.w*d3*rstd + be4.w);
    *(float4*)(out + off) = o4;
}

// ---------------------------------------------------------------- launch ----
extern "C" void kernel_launch(void* const* d_in, const int* in_sizes, int n_in,
                              void* d_out, int out_size, void* d_ws, size_t ws_size,
                              hipStream_t stream)
{
    (void)in_sizes; (void)n_in; (void)out_size;
    const float* x   = (const float*)d_in[0];
    const float* Wq  = (const float*)d_in[1];
    const float* bq  = (const float*)d_in[2];
    const float* Wk  = (const float*)d_in[3];
    const float* bk  = (const float*)d_in[4];
    const float* Wv  = (const float*)d_in[5];
    const float* bv  = (const float*)d_in[6];
    const float* lw  = (const float*)d_in[7];
    const float* lb  = (const float*)d_in[8];
    const float* Wo  = (const float*)d_in[9];
    const float* bo  = (const float*)d_in[10];
    const float* Wfc = (const float*)d_in[11];
    const float* bfc = (const float*)d_in[12];
    const float* g1  = (const float*)d_in[13];
    const float* b1  = (const float*)d_in[14];
    const float* g2  = (const float*)d_in[15];
    const float* b2  = (const float*)d_in[16];
    float* out = (float*)d_out;

    const size_t NB = (size_t)M_ * C_;         // 16777216 floats / buffer
    const size_t NEED = (3*NB + 2*131072 + 32768) * sizeof(float); // 193.1 MB
    if (ws_size < NEED) return;   // fail cleanly (absmax vs poison) not fault

    float* ws = (float*)d_ws;
    float* B1 = ws;                            // qr -> y -> t2
    float* B2 = ws + NB;                       // kr -> f
    float* B3 = ws + 2*NB;                     // v -> v5 -> attn_out -> xt
    float* sint  = ws + 3*NB;                  // 131072
    float* cost  = sint + 4096*32;             // 131072
    float* maskt = cost + 4096*32;             // 32768

    k_tables<<<512, 256, 0, stream>>>(sint, cost, maskt);
    k_gemm_qkv<<<dim3(1024,4,3), 256, 0, stream>>>(x, Wq,bq, Wk,bk, Wv,bv,
                                                   B1, B2, B3, sint, cost);
    k_conv<<<dim3(64,8,16), 256, 0, stream>>>(B3, lw, lb, out);       // lepe -> d_out
    k_attn<<<8192, 256, 0, stream>>>(B1, B2, B3, maskt, B3, 0);       // v5 in-place
    k_attn<<<8192, 256, 0, stream>>>(B1, B2, B3, maskt, B3, 1);       // attn_out in-place
    k_gemm_y<<<dim3(1024,4), 256, 0, stream>>>(B3, out, Wo, bo, B1);  // y -> B1
    k_transpose<<<dim3(128,8,16), 256, 0, stream>>>(x, B3, 256, 4096);// xt -> B3
    k_ln<<<16384, 256, 0, stream>>>(B3, B1, g1, b1, out);             // t1 -> d_out
    k_gemm_plain<<<dim3(1024,4), 256, 0, stream>>>(out, Wfc, bfc, B2);// f -> B2
    k_ln<<<16384, 256, 0, stream>>>(out, B2, g2, b2, B1);             // t2 -> B1
    k_transpose<<<dim3(8,128,16), 256, 0, stream>>>(B1, out, 4096, 256); // final
}

// Round 4
// 602.466 us; speedup vs baseline: 1.8370x; 1.8370x over previous
//
#include <hip/hip_runtime.h>
#include <math.h>

#define B_ 16
#define C_ 256
#define N_ 8
#define D_ 32
#define M_ (B_*64*64)              // 65536 rows
#define SCALING 0.17677669529663687f

typedef short  bf16x8 __attribute__((ext_vector_type(8)));
typedef float  f32x4  __attribute__((ext_vector_type(4)));
typedef unsigned short u16x8 __attribute__((ext_vector_type(8)));

__device__ __forceinline__ unsigned short f2bf(float f) {
    unsigned u = __float_as_uint(f);
    u += 0x7fffu + ((u >> 16) & 1u);
    return (unsigned short)(u >> 16);
}
__device__ __forceinline__ float bf2f(unsigned short h) {
    return __uint_as_float(((unsigned)h) << 16);
}
__device__ __forceinline__ void gld16(const void* g, void* l) {
    __builtin_amdgcn_global_load_lds(
        (const __attribute__((address_space(1))) unsigned*)g,
        (__attribute__((address_space(3))) unsigned*)l, 16, 0, 0);
}

// ---------------------------------------------------------------- tables ----
// sint_t/cost_t stored TRANSPOSED: [d][pos] (32 x 4096) so the MFMA epilogue
// (fixed col per lane, 4 consecutive rows per reg) can float4-load.
__global__ __launch_bounds__(256) void k_tables(float* __restrict__ sint_t,
                                                float* __restrict__ cost_t,
                                                float* __restrict__ maskt)
{
    int t = blockIdx.x * 256 + threadIdx.x;   // 131072 = 32*4096
    int d = t >> 12, p = t & 4095;
    int j = d >> 1;
    float ang = (float)pow(10000.0, -(double)j / 15.0);
    float arg = (float)p * ang;
    sint_t[t] = sinf(arg);
    cost_t[t] = cosf(arg);
    if (t < N_*64*64) {
        int n = t >> 12;
        int q = (t >> 6) & 63, k = t & 63;
        int ad = (q > k) ? (q - k) : (k - q);
        double decay = log(1.0 - exp2(-1.0 - 3.0 * (double)n / 8.0));
        maskt[t] = (float)((double)ad * decay);
    }
}

// ------------------------------------------------------- weight cvt+T -------
// Wt[n][k] = bf16(W[k][n] * scale)  (scale folds SCALING into Wk)
__global__ __launch_bounds__(256) void k_wcvt(
    const float* __restrict__ Wq, const float* __restrict__ Wk,
    const float* __restrict__ Wv, const float* __restrict__ Wo,
    const float* __restrict__ Wfc,
    unsigned short* __restrict__ Wqt, unsigned short* __restrict__ Wkt,
    unsigned short* __restrict__ Wvt, unsigned short* __restrict__ Wot,
    unsigned short* __restrict__ Wfct)
{
    __shared__ float t[32][33];
    int z = blockIdx.z;
    const float* W = z==0?Wq : z==1?Wk : z==2?Wv : z==3?Wo : Wfc;
    unsigned short* Wt = z==0?Wqt : z==1?Wkt : z==2?Wvt : z==3?Wot : Wfct;
    float sc = (z==1) ? SCALING : 1.0f;
    int tx = threadIdx.x & 31, ty = threadIdx.x >> 5;
    int bx = blockIdx.x * 32;   // n base
    int by = blockIdx.y * 32;   // k base
    #pragma unroll
    for (int j = 0; j < 4; ++j)
        t[ty + j*8][tx] = W[(by + ty + j*8) * 256 + bx + tx];  // t[k][n]
    __syncthreads();
    #pragma unroll
    for (int j = 0; j < 4; ++j)
        Wt[(bx + ty + j*8) * 256 + by + tx] = f2bf(t[tx][ty + j*8] * sc);
}

// ------------------------------------------------ prep: x -> xt f32 + x bf16
__global__ __launch_bounds__(256) void k_prep(const float* __restrict__ x,
                                              float* __restrict__ xt,
                                              unsigned short* __restrict__ xbf)
{
    __shared__ float t[32][33];
    int tx = threadIdx.x & 31, ty = threadIdx.x >> 5;
    int bx = blockIdx.x * 32;   // hw base
    int by = blockIdx.y * 32;   // c base
    size_t bo = (size_t)blockIdx.z * (256*4096);
    #pragma unroll
    for (int j = 0; j < 4; ++j)
        t[ty + j*8][tx] = x[bo + (size_t)(by + ty + j*8) * 4096 + bx + tx]; // t[c][hw]
    __syncthreads();
    #pragma unroll
    for (int j = 0; j < 4; ++j) {
        float v = t[tx][ty + j*8];
        size_t o = bo + (size_t)(bx + ty + j*8) * 256 + by + tx;
        xt[o] = v;
        xbf[o] = f2bf(v);
    }
}

// --------------------------------------------------------- MFMA GEMM core ---
// 128x128 tile, BK=32, 4 waves (2x2), each wave 64x64 = 4x4 16x16 frags.
// A (M,256) bf16 row-major; Bt (256,256) bf16 n-major. m97 structure.
__device__ __forceinline__ void mfma128(
    const unsigned short* A, const unsigned short* Bt, int r0, int c0,
    unsigned short* As, unsigned short* Bs, f32x4 acc[4][4])
{
    const int tid = threadIdx.x;
    const int w = tid >> 6, l = tid & 63;
    const int wr = w >> 1, wc = w & 1;
    const int fr = l & 15, fq = l >> 4;
    const int srow = 32*w + (l >> 2);       // staging row (+0 / +16)
    const int skel = (l & 3) * 8;           // k elems within row
    for (int kt = 0; kt < 256; kt += 32) {
        __syncthreads();
        gld16(A  + (size_t)(r0 + srow)      * 256 + kt + skel, As + (32*w)    * 32);
        gld16(A  + (size_t)(r0 + srow + 16) * 256 + kt + skel, As + (32*w+16) * 32);
        gld16(Bt + (size_t)(c0 + srow)      * 256 + kt + skel, Bs + (32*w)    * 32);
        gld16(Bt + (size_t)(c0 + srow + 16) * 256 + kt + skel, Bs + (32*w+16) * 32);
        __syncthreads();
        bf16x8 af[4], bfr[4];
        #pragma unroll
        for (int i = 0; i < 4; ++i)
            af[i] = *(const bf16x8*)(As + (wr*64 + i*16 + fr)*32 + fq*8);
        #pragma unroll
        for (int j = 0; j < 4; ++j)
            bfr[j] = *(const bf16x8*)(Bs + (wc*64 + j*16 + fr)*32 + fq*8);
        #pragma unroll
        for (int i = 0; i < 4; ++i)
            #pragma unroll
            for (int j = 0; j < 4; ++j)
                acc[i][j] = __builtin_amdgcn_mfma_f32_16x16x32_bf16(
                    af[i], bfr[j], acc[i][j], 0, 0, 0);
    }
}

// ------------------------------------------------------------- QKV GEMM -----
// z: 0=q,1=k,2=v. Epilogue: bias (k pre-scaled), theta shift (q,k), write
// bf16 to (b,n,pos,d). C/D layout: col=lane&15, row=(lane>>4)*4+reg.
__global__ __launch_bounds__(256) void k_qkv(
    const unsigned short* __restrict__ xbf,
    const unsigned short* __restrict__ Wqt, const unsigned short* __restrict__ Wkt,
    const unsigned short* __restrict__ Wvt,
    const float* __restrict__ bq, const float* __restrict__ bk,
    const float* __restrict__ bv,
    unsigned short* __restrict__ qb, unsigned short* __restrict__ kb,
    unsigned short* __restrict__ vb,
    const float* __restrict__ sint_t, const float* __restrict__ cost_t)
{
    __shared__ __align__(16) unsigned short As[4096], Bs[4096];
    int z = blockIdx.z;
    const unsigned short* Bt = z==0?Wqt : z==1?Wkt : Wvt;
    const float* bias = z==0?bq : z==1?bk : bv;
    unsigned short* dst = z==0?qb : z==1?kb : vb;
    int r0 = blockIdx.x * 128, c0 = blockIdx.y * 128;

    f32x4 acc[4][4];
    #pragma unroll
    for (int i = 0; i < 4; ++i)
        #pragma unroll
        for (int j = 0; j < 4; ++j) { f32x4 zr = {0.f,0.f,0.f,0.f}; acc[i][j] = zr; }
    mfma128(xbf, Bt, r0, c0, As, Bs, acc);

    int l = threadIdx.x & 63, w = threadIdx.x >> 6;
    int wr = w>>1, wc = w&1, fr = l&15, fq = l>>4;
    #pragma unroll
    for (int j = 0; j < 4; ++j) {
        int c = c0 + wc*64 + j*16 + fr;
        float bval = bias[c] * (z==1 ? SCALING : 1.0f);
        int n = c >> 5, dl = c & 31;
        #pragma unroll
        for (int i = 0; i < 4; ++i) {
            int rbase = r0 + wr*64 + i*16 + fq*4;
            int b = rbase >> 12;
            int pos0 = rbase & 4095;
            f32x4 v = acc[i][j];
            v[0] += bval; v[1] += bval; v[2] += bval; v[3] += bval;
            if (z < 2) {
                float4 s4 = *(const float4*)(sint_t + dl*4096 + pos0);
                float4 c4 = *(const float4*)(cost_t + dl*4096 + pos0);
                float p0 = __shfl_xor(v[0], 1);
                float p1 = __shfl_xor(v[1], 1);
                float p2 = __shfl_xor(v[2], 1);
                float p3 = __shfl_xor(v[3], 1);
                if (fr & 1) {
                    v[0] = v[0]*c4.x + p0*s4.x;  v[1] = v[1]*c4.y + p1*s4.y;
                    v[2] = v[2]*c4.z + p2*s4.z;  v[3] = v[3]*c4.w + p3*s4.w;
                } else {
                    v[0] = v[0]*c4.x - p0*s4.x;  v[1] = v[1]*c4.y - p1*s4.y;
                    v[2] = v[2]*c4.z - p2*s4.z;  v[3] = v[3]*c4.w - p3*s4.w;
                }
            }
            size_t obase = (size_t)(b*8 + n) * 131072;
            #pragma unroll
            for (int rg = 0; rg < 4; ++rg)
                dst[obase + (size_t)(pos0 + rg)*32 + dl] = f2bf(v[rg]);
        }
    }
}

// ---------------------------------------------------------- plain bf16 GEMM -
// out fp32 (M,256) = A(M,256)bf16 @ Bt^T + bias
__global__ __launch_bounds__(256) void k_gemm_bf(
    const unsigned short* __restrict__ A, const unsigned short* __restrict__ Bt,
    const float* __restrict__ bias, float* __restrict__ out)
{
    __shared__ __align__(16) unsigned short As[4096], Bs[4096];
    int r0 = blockIdx.x * 128, c0 = blockIdx.y * 128;
    f32x4 acc[4][4];
    #pragma unroll
    for (int i = 0; i < 4; ++i)
        #pragma unroll
        for (int j = 0; j < 4; ++j) { f32x4 zr = {0.f,0.f,0.f,0.f}; acc[i][j] = zr; }
    mfma128(A, Bt, r0, c0, As, Bs, acc);
    int l = threadIdx.x & 63, w = threadIdx.x >> 6;
    int wr = w>>1, wc = w&1, fr = l&15, fq = l>>4;
    #pragma unroll
    for (int j = 0; j < 4; ++j) {
        int c = c0 + wc*64 + j*16 + fr;
        float bval = bias[c];
        #pragma unroll
        for (int i = 0; i < 4; ++i) {
            int rbase = r0 + wr*64 + i*16 + fq*4;
            #pragma unroll
            for (int rg = 0; rg < 4; ++rg)
                out[(size_t)(rbase + rg)*256 + c] = acc[i][j][rg] + bval;
        }
    }
}

// -------------------------------------------------------------- LePE conv ---
// depthwise 5x5, pad 2. v bf16 (b,n,pos,d); out fp32 (b,h,w,c), c=n*32+d.
__global__ __launch_bounds__(256) void k_conv(
    const unsigned short* __restrict__ v, const float* __restrict__ cw,
    const float* __restrict__ cb, float* __restrict__ out)
{
    __shared__ float vs[5*68*36];
    __shared__ float wts[25*32];
    int h = blockIdx.x, n = blockIdx.y, b = blockIdx.z;
    int tid = threadIdx.x;
    for (int i = tid; i < 5*68*36; i += 256) vs[i] = 0.f;
    for (int i = tid; i < 800; i += 256) {
        int tap = i >> 5, d = i & 31;
        wts[i] = cw[tap*256 + n*32 + d];
    }
    __syncthreads();
    const unsigned short* vb_ = v + (size_t)((b*8 + n)*64) * 2048;
    #pragma unroll
    for (int it = 0; it < 5; ++it) {
        int f  = tid + it*256;        // 0..1279 : 5 rows x 256 u16x8 chunks
        int rr = f >> 8;
        int f2 = f & 255;
        int w  = f2 >> 2, d8 = (f2 & 3) * 8;
        int hh = h + rr - 2;
        if (hh >= 0 && hh < 64) {
            u16x8 vv = *(const u16x8*)(vb_ + hh*2048 + w*32 + d8);
            float* dp = vs + (rr*68 + w + 2)*36 + d8;
            #pragma unroll
            for (int e = 0; e < 8; ++e) dp[e] = bf2f(vv[e]);
        }
    }
    __syncthreads();
    int d = tid & 31, wq = tid >> 5;
    float wreg[25];
    #pragma unroll
    for (int t5 = 0; t5 < 25; ++t5) wreg[t5] = wts[t5*32 + d];
    float bias = cb[n*32 + d];
    for (int w = wq; w < 64; w += 8) {
        float acc = bias;
        #pragma unroll
        for (int dy = 0; dy < 5; ++dy)
            #pragma unroll
            for (int dx = 0; dx < 5; ++dx)
                acc = fmaf(vs[(dy*68 + w + dx)*36 + d], wreg[dy*5+dx], acc);
        out[(size_t)((b*64 + h)*64 + w)*256 + n*32 + d] = acc;
    }
}

// -------------------------------------------------------------- attention ---
// bf16 q/k/v in (b,n,pos,d). dir0: in-place v5 over own region. dir1: adds
// lepe (fp32, (M,256)) and writes bf16 A_y (M,256). Vb/Ob may alias (dir0).
__global__ __launch_bounds__(256) void k_attn(
    const unsigned short* __restrict__ Qb, const unsigned short* __restrict__ Kb,
    const unsigned short* Vb, const float* __restrict__ maskt,
    const float* __restrict__ lepe, unsigned short* Ob, int dir)
{
    __shared__ float Qs[64*36];
    __shared__ float Ks[64*36];
    __shared__ float Vs[64*36];
    __shared__ float Ps[64*68];
    int gid = blockIdx.x;
    int tid = threadIdx.x;
    int n = (gid >> 6) & 7;
    int base, sstr;
    if (dir == 0) { base = gid * 2048;                              sstr = 32;   }
    else          { base = (gid >> 6) * 131072 + (gid & 63) * 32;   sstr = 2048; }

    {
        int s  = tid >> 2;
        int d8 = (tid & 3) * 8;
        size_t ga = (size_t)base + (size_t)s*sstr + d8;
        int la = s*36 + d8;
        u16x8 qv = *(const u16x8*)(Qb + ga);
        u16x8 kv = *(const u16x8*)(Kb + ga);
        u16x8 vv = *(const u16x8*)(Vb + ga);
        #pragma unroll
        for (int e = 0; e < 8; ++e) {
            Qs[la+e] = bf2f(qv[e]);
            Ks[la+e] = bf2f(kv[e]);
            Vs[la+e] = bf2f(vv[e]);
        }
    }
    __syncthreads();

    int q = tid >> 2, kl = tid & 3;
    float4 qreg[8];
    #pragma unroll
    for (int j = 0; j < 8; ++j) qreg[j] = *(const float4*)(Qs + q*36 + j*4);
    float sv[16];
    const float* mrow = maskt + n*4096 + q*64;
    #pragma unroll
    for (int i = 0; i < 16; ++i) {
        int k = kl + i*4;
        const float4* krow = (const float4*)(Ks + k*36);
        float s = 0.f;
        #pragma unroll
        for (int j = 0; j < 8; ++j) {
            float4 kv = krow[j];
            s = fmaf(qreg[j].x, kv.x, s);
            s = fmaf(qreg[j].y, kv.y, s);
            s = fmaf(qreg[j].z, kv.z, s);
            s = fmaf(qreg[j].w, kv.w, s);
        }
        sv[i] = s + mrow[k];
    }
    float m = sv[0];
    #pragma unroll
    for (int i = 1; i < 16; ++i) m = fmaxf(m, sv[i]);
    m = fmaxf(m, __shfl_xor(m, 1, 4));
    m = fmaxf(m, __shfl_xor(m, 2, 4));
    float sum = 0.f;
    #pragma unroll
    for (int i = 0; i < 16; ++i) { sv[i] = __expf(sv[i] - m); sum += sv[i]; }
    sum += __shfl_xor(sum, 1, 4);
    sum += __shfl_xor(sum, 2, 4);
    float rinv = 1.f / sum;
    #pragma unroll
    for (int i = 0; i < 16; ++i) Ps[q*68 + kl + i*4] = sv[i] * rinv;
    __syncthreads();

    int d0 = (tid & 3) * 8;
    float o[8] = {0,0,0,0,0,0,0,0};
    for (int k = 0; k < 64; ++k) {
        float p = Ps[q*68 + k];
        float4 va  = *(const float4*)(Vs + k*36 + d0);
        float4 vb2 = *(const float4*)(Vs + k*36 + d0 + 4);
        o[0]=fmaf(p,va.x,o[0]);  o[1]=fmaf(p,va.y,o[1]);
        o[2]=fmaf(p,va.z,o[2]);  o[3]=fmaf(p,va.w,o[3]);
        o[4]=fmaf(p,vb2.x,o[4]); o[5]=fmaf(p,vb2.y,o[5]);
        o[6]=fmaf(p,vb2.z,o[6]); o[7]=fmaf(p,vb2.w,o[7]);
    }
    if (dir == 0) {
        u16x8 ov;
        #pragma unroll
        for (int e = 0; e < 8; ++e) ov[e] = f2bf(o[e]);
        *(u16x8*)(Ob + (size_t)base + q*32 + d0) = ov;
    } else {
        int b = gid >> 9, w2 = gid & 63;
        size_t lrow = ((size_t)(b*64 + q)*64 + w2)*256 + n*32 + d0;
        float4 l0 = *(const float4*)(lepe + lrow);
        float4 l1 = *(const float4*)(lepe + lrow + 4);
        o[0]+=l0.x; o[1]+=l0.y; o[2]+=l0.z; o[3]+=l0.w;
        o[4]+=l1.x; o[5]+=l1.y; o[6]+=l1.z; o[7]+=l1.w;
        u16x8 ov;
        #pragma unroll
        for (int e = 0; e < 8; ++e) ov[e] = f2bf(o[e]);
        *(u16x8*)(Ob + lrow) = ov;
    }
}

// ---------------------------------------------------------------- LN(a+b) ---
// out may alias A (row-wise in-place). Optionally dual-write bf16.
template<bool BFOUT>
__global__ __launch_bounds__(256) void k_ln(
    const float* A, const float* __restrict__ Bv,
    const float* __restrict__ g, const float* __restrict__ bb,
    float* out, unsigned short* __restrict__ outbf)
{
    int row  = blockIdx.x * 4 + (threadIdx.x >> 6);
    int lane = threadIdx.x & 63;
    size_t off = (size_t)row * 256 + lane*4;
    float4 a4 = *(const float4*)(A + off);
    float4 b4 = *(const float4*)(Bv + off);
    float v0=a4.x+b4.x, v1=a4.y+b4.y, v2=a4.z+b4.z, v3=a4.w+b4.w;
    float s = v0+v1+v2+v3;
    #pragma unroll
    for (int mm = 1; mm < 64; mm <<= 1) s += __shfl_xor(s, mm, 64);
    float mean = s * (1.0f/256.0f);
    float d0=v0-mean, d1=v1-mean, d2=v2-mean, d3=v3-mean;
    float qq = d0*d0 + d1*d1 + d2*d2 + d3*d3;
    #pragma unroll
    for (int mm = 1; mm < 64; mm <<= 1) qq += __shfl_xor(qq, mm, 64);
    float rstd = rsqrtf(qq * (1.0f/256.0f) + 1e-6f);
    float4 g4  = *(const float4*)(g + lane*4);
    float4 be4 = *(const float4*)(bb + lane*4);
    float o0 = g4.x*d0*rstd + be4.x, o1 = g4.y*d1*rstd + be4.y;
    float o2 = g4.z*d2*rstd + be4.z, o3 = g4.w*d3*rstd + be4.w;
    *(float4*)(out + off) = make_float4(o0, o1, o2, o3);
    if (BFOUT) {
        ushort4 ov = make_ushort4(f2bf(o0), f2bf(o1), f2bf(o2), f2bf(o3));
        *(ushort4*)(outbf + off) = ov;
    }
}

// ------------------------------------------------------------- transpose ----
__global__ __launch_bounds__(256) void k_transpose(const float* __restrict__ src,
                                                   float* __restrict__ dst,
                                                   int rows, int cols)
{
    __shared__ float t[32][33];
    int tx = threadIdx.x & 31, ty = threadIdx.x >> 5;
    int bx = blockIdx.x * 32, by = blockIdx.y * 32;
    size_t bo = (size_t)blockIdx.z * rows * cols;
    #pragma unroll
    for (int j = 0; j < 4; ++j)
        t[ty + j*8][tx] = src[bo + (size_t)(by + ty + j*8) * cols + bx + tx];
    __syncthreads();
    #pragma unroll
    for (int j = 0; j < 4; ++j)
        dst[bo + (size_t)(bx + ty + j*8) * rows + by + tx] = t[tx][ty + j*8];
}

// ---------------------------------------------------------------- launch ----
extern "C" void kernel_launch(void* const* d_in, const int* in_sizes, int n_in,
                              void* d_out, int out_size, void* d_ws, size_t ws_size,
                              hipStream_t stream)
{
    (void)in_sizes; (void)n_in; (void)out_size;
    const float* x   = (const float*)d_in[0];
    const float* Wq  = (const float*)d_in[1];
    const float* bq  = (const float*)d_in[2];
    const float* Wk  = (const float*)d_in[3];
    const float* bk  = (const float*)d_in[4];
    const float* Wv  = (const float*)d_in[5];
    const float* bv  = (const float*)d_in[6];
    const float* lw  = (const float*)d_in[7];
    const float* lb  = (const float*)d_in[8];
    const float* Wo  = (const float*)d_in[9];
    const float* bo  = (const float*)d_in[10];
    const float* Wfc = (const float*)d_in[11];
    const float* bfc = (const float*)d_in[12];
    const float* g1  = (const float*)d_in[13];
    const float* b1  = (const float*)d_in[14];
    const float* g2  = (const float*)d_in[15];
    const float* b2  = (const float*)d_in[16];
    float* out = (float*)d_out;

    const size_t NBB = 67108864;   // 64 MB
    const size_t NEED = 3*NBB + 2*524288 + 131072 + 5*131072;  // 193.75 MB
    if (ws_size < NEED) return;    // clean fail, not a fault

    char* wsb = (char*)d_ws;
    float*          xt   = (float*)wsb;                        // [0,64M) t1 in-place
    unsigned short* xbf  = (unsigned short*)(wsb + NBB);       // [64,96M) xbf/A_y/t1bf
    unsigned short* qb   = (unsigned short*)(wsb + NBB + NBB/2);     // [96,128M)
    unsigned short* kb   = (unsigned short*)(wsb + 2*NBB);           // [128,160M)
    unsigned short* vb   = (unsigned short*)(wsb + 2*NBB + NBB/2);   // [160,192M)
    float*          yb   = (float*)(wsb + NBB + NBB/2);        // y/t2 over qb+kb
    float* sint_t = (float*)(wsb + 3*NBB);
    float* cost_t = sint_t + 131072;
    float* maskt  = cost_t + 131072;
    unsigned short* Wqt  = (unsigned short*)(maskt + 32768);
    unsigned short* Wkt  = Wqt + 65536;
    unsigned short* Wvt  = Wkt + 65536;
    unsigned short* Wot  = Wvt + 65536;
    unsigned short* Wfct = Wot + 65536;

    k_tables<<<512, 256, 0, stream>>>(sint_t, cost_t, maskt);
    k_wcvt<<<dim3(8,8,5), 256, 0, stream>>>(Wq,Wk,Wv,Wo,Wfc,
                                            Wqt,Wkt,Wvt,Wot,Wfct);
    k_prep<<<dim3(128,8,16), 256, 0, stream>>>(x, xt, xbf);
    k_qkv<<<dim3(512,2,3), 256, 0, stream>>>(xbf, Wqt,Wkt,Wvt, bq,bk,bv,
                                             qb,kb,vb, sint_t,cost_t);
    k_conv<<<dim3(64,8,16), 256, 0, stream>>>(vb, lw, lb, out);     // lepe -> d_out
    k_attn<<<8192, 256, 0, stream>>>(qb, kb, vb, maskt, nullptr, vb, 0); // v5 in-place
    k_attn<<<8192, 256, 0, stream>>>(qb, kb, vb, maskt, out, xbf, 1);    // A_y (+lepe)
    k_gemm_bf<<<dim3(512,2), 256, 0, stream>>>(xbf, Wot, bo, yb);        // y
    k_ln<true><<<16384, 256, 0, stream>>>(xt, yb, g1, b1, xt, xbf);      // t1 + t1bf
    k_gemm_bf<<<dim3(512,2), 256, 0, stream>>>(xbf, Wfct, bfc, out);     // f -> d_out
    k_ln<false><<<16384, 256, 0, stream>>>(xt, out, g2, b2, yb, nullptr);// t2
    k_transpose<<<dim3(8,128,16), 256, 0, stream>>>(yb, out, 4096, 256); // final
}

// Round 6
// 514.691 us; speedup vs baseline: 2.1502x; 1.1705x over previous
//
#include <hip/hip_runtime.h>
#include <math.h>

#define B_ 16
#define C_ 256
#define N_ 8
#define D_ 32
#define M_ (B_*64*64)              // 65536 rows
#define SCALING 0.17677669529663687f

typedef short  bf16x8 __attribute__((ext_vector_type(8)));
typedef float  f32x4  __attribute__((ext_vector_type(4)));
typedef unsigned short u16x8 __attribute__((ext_vector_type(8)));

__device__ __forceinline__ unsigned short f2bf(float f) {
    unsigned u = __float_as_uint(f);
    u += 0x7fffu + ((u >> 16) & 1u);
    return (unsigned short)(u >> 16);
}
__device__ __forceinline__ float bf2f(unsigned short h) {
    return __uint_as_float(((unsigned)h) << 16);
}
__device__ __forceinline__ void gld16(const void* g, void* l) {
    __builtin_amdgcn_global_load_lds(
        (const __attribute__((address_space(1))) unsigned*)g,
        (__attribute__((address_space(3))) unsigned*)l, 16, 0, 0);
}

// ---------------------------------------------------------------- tables ----
// sint_t/cost_t stored TRANSPOSED: [d][pos] (32 x 4096) so the MFMA epilogue
// (fixed col per lane, 4 consecutive rows per reg) can float4-load.
__global__ __launch_bounds__(256) void k_tables(float* __restrict__ sint_t,
                                                float* __restrict__ cost_t)
{
    int t = blockIdx.x * 256 + threadIdx.x;   // 131072 = 32*4096
    int d = t >> 12, p = t & 4095;
    int j = d >> 1;
    float ang = (float)pow(10000.0, -(double)j / 15.0);
    float arg = (float)p * ang;
    sint_t[t] = sinf(arg);
    cost_t[t] = cosf(arg);
}

// ------------------------------------------------------- weight cvt+T -------
// Wt[n][k] = bf16(W[k][n] * scale)  (scale folds SCALING into Wk)
__global__ __launch_bounds__(256) void k_wcvt(
    const float* __restrict__ Wq, const float* __restrict__ Wk,
    const float* __restrict__ Wv, const float* __restrict__ Wo,
    const float* __restrict__ Wfc,
    unsigned short* __restrict__ Wqt, unsigned short* __restrict__ Wkt,
    unsigned short* __restrict__ Wvt, unsigned short* __restrict__ Wot,
    unsigned short* __restrict__ Wfct)
{
    __shared__ float t[32][33];
    int z = blockIdx.z;
    const float* W = z==0?Wq : z==1?Wk : z==2?Wv : z==3?Wo : Wfc;
    unsigned short* Wt = z==0?Wqt : z==1?Wkt : z==2?Wvt : z==3?Wot : Wfct;
    float sc = (z==1) ? SCALING : 1.0f;
    int tx = threadIdx.x & 31, ty = threadIdx.x >> 5;
    int bx = blockIdx.x * 32;   // n base
    int by = blockIdx.y * 32;   // k base
    #pragma unroll
    for (int j = 0; j < 4; ++j)
        t[ty + j*8][tx] = W[(by + ty + j*8) * 256 + bx + tx];  // t[k][n]
    __syncthreads();
    #pragma unroll
    for (int j = 0; j < 4; ++j)
        Wt[(bx + ty + j*8) * 256 + by + tx] = f2bf(t[tx][ty + j*8] * sc);
}

// ------------------------------------------------ prep: x -> xt f32 + x bf16
__global__ __launch_bounds__(256) void k_prep(const float* __restrict__ x,
                                              float* __restrict__ xt,
                                              unsigned short* __restrict__ xbf)
{
    __shared__ float t[32][33];
    int tx = threadIdx.x & 31, ty = threadIdx.x >> 5;
    int bx = blockIdx.x * 32;   // hw base
    int by = blockIdx.y * 32;   // c base
    size_t bo = (size_t)blockIdx.z * (256*4096);
    #pragma unroll
    for (int j = 0; j < 4; ++j)
        t[ty + j*8][tx] = x[bo + (size_t)(by + ty + j*8) * 4096 + bx + tx]; // t[c][hw]
    __syncthreads();
    #pragma unroll
    for (int j = 0; j < 4; ++j) {
        float v = t[tx][ty + j*8];
        size_t o = bo + (size_t)(bx + ty + j*8) * 256 + by + tx;
        xt[o] = v;
        xbf[o] = f2bf(v);
    }
}

// --------------------------------------------------------- MFMA GEMM core ---
// 128x128 tile, BK=32, 4 waves (2x2), each wave 64x64 = 4x4 16x16 frags.
// A (M,256) bf16 row-major; Bt (256,256) bf16 n-major. m97 structure.
__device__ __forceinline__ void mfma128(
    const unsigned short* A, const unsigned short* Bt, int r0, int c0,
    unsigned short* As, unsigned short* Bs, f32x4 acc[4][4])
{
    const int tid = threadIdx.x;
    const int w = tid >> 6, l = tid & 63;
    const int wr = w >> 1, wc = w & 1;
    const int fr = l & 15, fq = l >> 4;
    const int srow = 32*w + (l >> 2);       // staging row (+0 / +16)
    const int skel = (l & 3) * 8;           // k elems within row
    for (int kt = 0; kt < 256; kt += 32) {
        __syncthreads();
        gld16(A  + (size_t)(r0 + srow)      * 256 + kt + skel, As + (32*w)    * 32);
        gld16(A  + (size_t)(r0 + srow + 16) * 256 + kt + skel, As + (32*w+16) * 32);
        gld16(Bt + (size_t)(c0 + srow)      * 256 + kt + skel, Bs + (32*w)    * 32);
        gld16(Bt + (size_t)(c0 + srow + 16) * 256 + kt + skel, Bs + (32*w+16) * 32);
        __syncthreads();
        bf16x8 af[4], bfr[4];
        #pragma unroll
        for (int i = 0; i < 4; ++i)
            af[i] = *(const bf16x8*)(As + (wr*64 + i*16 + fr)*32 + fq*8);
        #pragma unroll
        for (int j = 0; j < 4; ++j)
            bfr[j] = *(const bf16x8*)(Bs + (wc*64 + j*16 + fr)*32 + fq*8);
        #pragma unroll
        for (int i = 0; i < 4; ++i)
            #pragma unroll
            for (int j = 0; j < 4; ++j)
                acc[i][j] = __builtin_amdgcn_mfma_f32_16x16x32_bf16(
                    af[i], bfr[j], acc[i][j], 0, 0, 0);
    }
}

// ------------------------------------------------------------- QKV GEMM -----
// z: 0=q,1=k,2=v. Epilogue: bias (k pre-scaled), theta shift (q,k), write
// bf16 to (b,n,pos,d). C/D layout: col=lane&15, row=(lane>>4)*4+reg.
__global__ __launch_bounds__(256) void k_qkv(
    const unsigned short* __restrict__ xbf,
    const unsigned short* __restrict__ Wqt, const unsigned short* __restrict__ Wkt,
    const unsigned short* __restrict__ Wvt,
    const float* __restrict__ bq, const float* __restrict__ bk,
    const float* __restrict__ bv,
    unsigned short* __restrict__ qb, unsigned short* __restrict__ kb,
    unsigned short* __restrict__ vb,
    const float* __restrict__ sint_t, const float* __restrict__ cost_t)
{
    __shared__ __align__(16) unsigned short As[4096], Bs[4096];
    int z = blockIdx.z;
    const unsigned short* Bt = z==0?Wqt : z==1?Wkt : Wvt;
    const float* bias = z==0?bq : z==1?bk : bv;
    unsigned short* dst = z==0?qb : z==1?kb : vb;
    int r0 = blockIdx.x * 128, c0 = blockIdx.y * 128;

    f32x4 acc[4][4];
    #pragma unroll
    for (int i = 0; i < 4; ++i)
        #pragma unroll
        for (int j = 0; j < 4; ++j) { f32x4 zr = {0.f,0.f,0.f,0.f}; acc[i][j] = zr; }
    mfma128(xbf, Bt, r0, c0, As, Bs, acc);

    int l = threadIdx.x & 63, w = threadIdx.x >> 6;
    int wr = w>>1, wc = w&1, fr = l&15, fq = l>>4;
    #pragma unroll
    for (int j = 0; j < 4; ++j) {
        int c = c0 + wc*64 + j*16 + fr;
        float bval = bias[c] * (z==1 ? SCALING : 1.0f);
        int n = c >> 5, dl = c & 31;
        #pragma unroll
        for (int i = 0; i < 4; ++i) {
            int rbase = r0 + wr*64 + i*16 + fq*4;
            int b = rbase >> 12;
            int pos0 = rbase & 4095;
            f32x4 v = acc[i][j];
            v[0] += bval; v[1] += bval; v[2] += bval; v[3] += bval;
            if (z < 2) {
                float4 s4 = *(const float4*)(sint_t + dl*4096 + pos0);
                float4 c4 = *(const float4*)(cost_t + dl*4096 + pos0);
                float p0 = __shfl_xor(v[0], 1);
                float p1 = __shfl_xor(v[1], 1);
                float p2 = __shfl_xor(v[2], 1);
                float p3 = __shfl_xor(v[3], 1);
                if (fr & 1) {
                    v[0] = v[0]*c4.x + p0*s4.x;  v[1] = v[1]*c4.y + p1*s4.y;
                    v[2] = v[2]*c4.z + p2*s4.z;  v[3] = v[3]*c4.w + p3*s4.w;
                } else {
                    v[0] = v[0]*c4.x - p0*s4.x;  v[1] = v[1]*c4.y - p1*s4.y;
                    v[2] = v[2]*c4.z - p2*s4.z;  v[3] = v[3]*c4.w - p3*s4.w;
                }
            }
            size_t obase = (size_t)(b*8 + n) * 131072;
            #pragma unroll
            for (int rg = 0; rg < 4; ++rg)
                dst[obase + (size_t)(pos0 + rg)*32 + dl] = f2bf(v[rg]);
        }
    }
}

// ---------------------------------------------------------- plain bf16 GEMM -
// out fp32 (M,256) = A(M,256)bf16 @ Bt^T + bias
__global__ __launch_bounds__(256) void k_gemm_bf(
    const unsigned short* __restrict__ A, const unsigned short* __restrict__ Bt,
    const float* __restrict__ bias, float* __restrict__ out)
{
    __shared__ __align__(16) unsigned short As[4096], Bs[4096];
    int r0 = blockIdx.x * 128, c0 = blockIdx.y * 128;
    f32x4 acc[4][4];
    #pragma unroll
    for (int i = 0; i < 4; ++i)
        #pragma unroll
        for (int j = 0; j < 4; ++j) { f32x4 zr = {0.f,0.f,0.f,0.f}; acc[i][j] = zr; }
    mfma128(A, Bt, r0, c0, As, Bs, acc);
    int l = threadIdx.x & 63, w = threadIdx.x >> 6;
    int wr = w>>1, wc = w&1, fr = l&15, fq = l>>4;
    #pragma unroll
    for (int j = 0; j < 4; ++j) {
        int c = c0 + wc*64 + j*16 + fr;
        float bval = bias[c];
        #pragma unroll
        for (int i = 0; i < 4; ++i) {
            int rbase = r0 + wr*64 + i*16 + fq*4;
            #pragma unroll
            for (int rg = 0; rg < 4; ++rg)
                out[(size_t)(rbase + rg)*256 + c] = acc[i][j][rg] + bval;
        }
    }
}

// -------------------------------------------------------------- LePE conv ---
// depthwise 5x5, pad 2. v bf16 (b,n,pos,d); out fp32 (b,h,w,c), c=n*32+d.
__global__ __launch_bounds__(256) void k_conv(
    const unsigned short* __restrict__ v, const float* __restrict__ cw,
    const float* __restrict__ cb, float* __restrict__ out)
{
    __shared__ float vs[5*68*36];
    __shared__ float wts[25*32];
    int h = blockIdx.x, n = blockIdx.y, b = blockIdx.z;
    int tid = threadIdx.x;
    for (int i = tid; i < 5*68*36; i += 256) vs[i] = 0.f;
    for (int i = tid; i < 800; i += 256) {
        int tap = i >> 5, d = i & 31;
        wts[i] = cw[tap*256 + n*32 + d];
    }
    __syncthreads();
    const unsigned short* vb_ = v + (size_t)((b*8 + n)*64) * 2048;
    #pragma unroll
    for (int it = 0; it < 5; ++it) {
        int f  = tid + it*256;        // 0..1279 : 5 rows x 256 u16x8 chunks
        int rr = f >> 8;
        int f2 = f & 255;
        int w  = f2 >> 2, d8 = (f2 & 3) * 8;
        int hh = h + rr - 2;
        if (hh >= 0 && hh < 64) {
            u16x8 vv = *(const u16x8*)(vb_ + hh*2048 + w*32 + d8);
            float* dp = vs + (rr*68 + w + 2)*36 + d8;
            #pragma unroll
            for (int e = 0; e < 8; ++e) dp[e] = bf2f(vv[e]);
        }
    }
    __syncthreads();
    int d = tid & 31, wq = tid >> 5;
    float wreg[25];
    #pragma unroll
    for (int t5 = 0; t5 < 25; ++t5) wreg[t5] = wts[t5*32 + d];
    float bias = cb[n*32 + d];
    for (int w = wq; w < 64; w += 8) {
        float acc = bias;
        #pragma unroll
        for (int dy = 0; dy < 5; ++dy)
            #pragma unroll
            for (int dx = 0; dx < 5; ++dx)
                acc = fmaf(vs[(dy*68 + w + dx)*36 + d], wreg[dy*5+dx], acc);
        out[(size_t)((b*64 + h)*64 + w)*256 + n*32 + d] = acc;
    }
}

// -------------------------------------------------------- MFMA attention ----
// One wave per (b,n,seq-group). QK^T and PV on matrix cores; mask analytic;
// softmax via shfl over 16-lane groups; P and V^T staged in wave-private LDS
// (no barriers). dir0: in-place v5 over own V region. dir1: +lepe -> bf16 A_y.
__global__ __launch_bounds__(256, 3) void k_attn_mfma(
    const unsigned short* __restrict__ Qb, const unsigned short* __restrict__ Kb,
    const unsigned short* Vb, const float* __restrict__ lepe,
    unsigned short* Ob, int dir)
{
    __shared__ unsigned short S[4 * 4864];   // per wave: Vt[32][72] + Ps[64][40]
    int tid = threadIdx.x;
    int wv = tid >> 6, l = tid & 63;
    int gid = blockIdx.x * 4 + wv;
    int n = (gid >> 6) & 7;
    int c = l & 15, g = l >> 4;
    size_t base; int sstr;
    if (dir == 0) { base = (size_t)gid * 2048;                               sstr = 32;   }
    else          { base = (size_t)(gid >> 6) * 131072 + (size_t)(gid & 63) * 32; sstr = 2048; }

    unsigned short* Vt = S + wv * 4864;     // [32][72] : V^T (d, k)
    unsigned short* Ps = Vt + 2304;         // [64][40] : P half (k-block of 32)

    float decayf = (float)log(1.0 - exp2(-1.0 - 3.0 * (double)n / 8.0));

    // ---- stage V^T (lane l owns pos l) ----
    #pragma unroll
    for (int it = 0; it < 4; ++it) {
        u16x8 vv = *(const u16x8*)(Vb + base + (size_t)l * sstr + it*8);
        #pragma unroll
        for (int e = 0; e < 8; ++e)
            Vt[(it*8 + e)*72 + l] = vv[e];
    }

    // ---- Q/K fragments straight from global (A/B frag: row=c, k=g*8..) ----
    bf16x8 qf[4], kf[4];
    #pragma unroll
    for (int i = 0; i < 4; ++i) {
        qf[i] = *(const bf16x8*)(Qb + base + (size_t)(i*16 + c) * sstr + g*8);
        kf[i] = *(const bf16x8*)(Kb + base + (size_t)(i*16 + c) * sstr + g*8);
    }

    // ---- QK^T : 16 MFMA ----
    f32x4 acc[4][4];
    #pragma unroll
    for (int i = 0; i < 4; ++i)
        #pragma unroll
        for (int j = 0; j < 4; ++j) { f32x4 zr = {0.f,0.f,0.f,0.f}; acc[i][j] = zr; }
    #pragma unroll
    for (int i = 0; i < 4; ++i)
        #pragma unroll
        for (int j = 0; j < 4; ++j)
            acc[i][j] = __builtin_amdgcn_mfma_f32_16x16x32_bf16(
                qf[i], kf[j], acc[i][j], 0, 0, 0);

    // ---- mask + softmax (row q = i*16 + g*4 + r; col k = j*16 + c) ----
    float rinv[4][4];
    #pragma unroll
    for (int i = 0; i < 4; ++i) {
        #pragma unroll
        for (int r = 0; r < 4; ++r) {
            float qi = (float)(i*16 + g*4 + r);
            float m = -1e30f;
            #pragma unroll
            for (int j = 0; j < 4; ++j) {
                float ki = (float)(j*16 + c);
                acc[i][j][r] += fabsf(qi - ki) * decayf;
                m = fmaxf(m, acc[i][j][r]);
            }
            m = fmaxf(m, __shfl_xor(m, 1, 16));
            m = fmaxf(m, __shfl_xor(m, 2, 16));
            m = fmaxf(m, __shfl_xor(m, 4, 16));
            m = fmaxf(m, __shfl_xor(m, 8, 16));
            float s = 0.f;
            #pragma unroll
            for (int j = 0; j < 4; ++j) {
                float e = __expf(acc[i][j][r] - m);
                acc[i][j][r] = e;
                s += e;
            }
            s += __shfl_xor(s, 1, 16);
            s += __shfl_xor(s, 2, 16);
            s += __shfl_xor(s, 4, 16);
            s += __shfl_xor(s, 8, 16);
            rinv[i][r] = 1.f / s;
        }
    }

    // ---- PV (split over k-halves through LDS): 16 MFMA ----
    f32x4 o[4][2];
    #pragma unroll
    for (int i = 0; i < 4; ++i) { f32x4 zr = {0.f,0.f,0.f,0.f}; o[i][0] = zr; o[i][1] = zr; }
    #pragma unroll
    for (int s = 0; s < 2; ++s) {
        #pragma unroll
        for (int i = 0; i < 4; ++i)
            #pragma unroll
            for (int r = 0; r < 4; ++r)
                #pragma unroll
                for (int jj = 0; jj < 2; ++jj)
                    Ps[(i*16 + g*4 + r)*40 + jj*16 + c] = f2bf(acc[i][2*s + jj][r]);
        bf16x8 vf0 = *(const bf16x8*)(Vt + (     c)*72 + s*32 + g*8);
        bf16x8 vf1 = *(const bf16x8*)(Vt + (16 + c)*72 + s*32 + g*8);
        #pragma unroll
        for (int i = 0; i < 4; ++i) {
            bf16x8 pa = *(const bf16x8*)(Ps + (i*16 + c)*40 + g*8);
            o[i][0] = __builtin_amdgcn_mfma_f32_16x16x32_bf16(pa, vf0, o[i][0], 0, 0, 0);
            o[i][1] = __builtin_amdgcn_mfma_f32_16x16x32_bf16(pa, vf1, o[i][1], 0, 0, 0);
        }
    }

    // ---- epilogue: normalize, write (row q; col d = nn*16 + c) ----
    #pragma unroll
    for (int i = 0; i < 4; ++i) {
        #pragma unroll
        for (int r = 0; r < 4; ++r) {
            int q = i*16 + g*4 + r;
            float ri = rinv[i][r];
            if (dir == 0) {
                Ob[base + (size_t)q*32 + c]      = f2bf(o[i][0][r] * ri);
                Ob[base + (size_t)q*32 + 16 + c] = f2bf(o[i][1][r] * ri);
            } else {
                int b = gid >> 9, w2 = gid & 63;
                size_t idx = ((size_t)((b*64 + q)*64 + w2))*256 + n*32 + c;
                Ob[idx]      = f2bf(o[i][0][r] * ri + lepe[idx]);
                Ob[idx + 16] = f2bf(o[i][1][r] * ri + lepe[idx + 16]);
            }
        }
    }
}

// ---------------------------------------------------------------- LN(a+b) ---
// out may alias A (row-wise in-place). Optionally dual-write bf16.
template<bool BFOUT>
__global__ __launch_bounds__(256) void k_ln(
    const float* A, const float* __restrict__ Bv,
    const float* __restrict__ g, const float* __restrict__ bb,
    float* out, unsigned short* __restrict__ outbf)
{
    int row  = blockIdx.x * 4 + (threadIdx.x >> 6);
    int lane = threadIdx.x & 63;
    size_t off = (size_t)row * 256 + lane*4;
    float4 a4 = *(const float4*)(A + off);
    float4 b4 = *(const float4*)(Bv + off);
    float v0=a4.x+b4.x, v1=a4.y+b4.y, v2=a4.z+b4.z, v3=a4.w+b4.w;
    float s = v0+v1+v2+v3;
    #pragma unroll
    for (int mm = 1; mm < 64; mm <<= 1) s += __shfl_xor(s, mm, 64);
    float mean = s * (1.0f/256.0f);
    float d0=v0-mean, d1=v1-mean, d2=v2-mean, d3=v3-mean;
    float qq = d0*d0 + d1*d1 + d2*d2 + d3*d3;
    #pragma unroll
    for (int mm = 1; mm < 64; mm <<= 1) qq += __shfl_xor(qq, mm, 64);
    float rstd = rsqrtf(qq * (1.0f/256.0f) + 1e-6f);
    float4 g4  = *(const float4*)(g + lane*4);
    float4 be4 = *(const float4*)(bb + lane*4);
    float o0 = g4.x*d0*rstd + be4.x, o1 = g4.y*d1*rstd + be4.y;
    float o2 = g4.z*d2*rstd + be4.z, o3 = g4.w*d3*rstd + be4.w;
    *(float4*)(out + off) = make_float4(o0, o1, o2, o3);
    if (BFOUT) {
        ushort4 ov = make_ushort4(f2bf(o0), f2bf(o1), f2bf(o2), f2bf(o3));
        *(ushort4*)(outbf + off) = ov;
    }
}

// ------------------------------------------------------------- transpose ----
__global__ __launch_bounds__(256) void k_transpose(const float* __restrict__ src,
                                                   float* __restrict__ dst,
                                                   int rows, int cols)
{
    __shared__ float t[32][33];
    int tx = threadIdx.x & 31, ty = threadIdx.x >> 5;
    int bx = blockIdx.x * 32, by = blockIdx.y * 32;
    size_t bo = (size_t)blockIdx.z * rows * cols;
    #pragma unroll
    for (int j = 0; j < 4; ++j)
        t[ty + j*8][tx] = src[bo + (size_t)(by + ty + j*8) * cols + bx + tx];
    __syncthreads();
    #pragma unroll
    for (int j = 0; j < 4; ++j)
        dst[bo + (size_t)(bx + ty + j*8) * rows + by + tx] = t[tx][ty + j*8];
}

// ---------------------------------------------------------------- launch ----
extern "C" void kernel_launch(void* const* d_in, const int* in_sizes, int n_in,
                              void* d_out, int out_size, void* d_ws, size_t ws_size,
                              hipStream_t stream)
{
    (void)in_sizes; (void)n_in; (void)out_size;
    const float* x   = (const float*)d_in[0];
    const float* Wq  = (const float*)d_in[1];
    const float* bq  = (const float*)d_in[2];
    const float* Wk  = (const float*)d_in[3];
    const float* bk  = (const float*)d_in[4];
    const float* Wv  = (const float*)d_in[5];
    const float* bv  = (const float*)d_in[6];
    const float* lw  = (const float*)d_in[7];
    const float* lb  = (const float*)d_in[8];
    const float* Wo  = (const float*)d_in[9];
    const float* bo  = (const float*)d_in[10];
    const float* Wfc = (const float*)d_in[11];
    const float* bfc = (const float*)d_in[12];
    const float* g1  = (const float*)d_in[13];
    const float* b1  = (const float*)d_in[14];
    const float* g2  = (const float*)d_in[15];
    const float* b2  = (const float*)d_in[16];
    float* out = (float*)d_out;

    const size_t NBB = 67108864;   // 64 MB
    const size_t NEED = 3*NBB + 2*524288 + 5*131072;
    if (ws_size < NEED) return;    // clean fail, not a fault

    char* wsb = (char*)d_ws;
    float*          xt   = (float*)wsb;                        // [0,64M) t1 in-place
    unsigned short* xbf  = (unsigned short*)(wsb + NBB);       // [64,96M) xbf/A_y/t1bf
    unsigned short* qb   = (unsigned short*)(wsb + NBB + NBB/2);     // [96,128M)
    unsigned short* kb   = (unsigned short*)(wsb + 2*NBB);           // [128,160M)
    unsigned short* vb   = (unsigned short*)(wsb + 2*NBB + NBB/2);   // [160,192M)
    float*          yb   = (float*)(wsb + NBB + NBB/2);        // y/t2 over qb+kb
    float* sint_t = (float*)(wsb + 3*NBB);
    float* cost_t = sint_t + 131072;
    unsigned short* Wqt  = (unsigned short*)(cost_t + 131072);
    unsigned short* Wkt  = Wqt + 65536;
    unsigned short* Wvt  = Wkt + 65536;
    unsigned short* Wot  = Wvt + 65536;
    unsigned short* Wfct = Wot + 65536;

    k_tables<<<512, 256, 0, stream>>>(sint_t, cost_t);
    k_wcvt<<<dim3(8,8,5), 256, 0, stream>>>(Wq,Wk,Wv,Wo,Wfc,
                                            Wqt,Wkt,Wvt,Wot,Wfct);
    k_prep<<<dim3(128,8,16), 256, 0, stream>>>(x, xt, xbf);
    k_qkv<<<dim3(512,2,3), 256, 0, stream>>>(xbf, Wqt,Wkt,Wvt, bq,bk,bv,
                                             qb,kb,vb, sint_t,cost_t);
    k_conv<<<dim3(64,8,16), 256, 0, stream>>>(vb, lw, lb, out);         // lepe -> d_out
    k_attn_mfma<<<2048, 256, 0, stream>>>(qb, kb, vb, nullptr, vb, 0);  // v5 in-place
    k_attn_mfma<<<2048, 256, 0, stream>>>(qb, kb, vb, out, xbf, 1);     // A_y (+lepe)
    k_gemm_bf<<<dim3(512,2), 256, 0, stream>>>(xbf, Wot, bo, yb);       // y
    k_ln<true><<<16384, 256, 0, stream>>>(xt, yb, g1, b1, xt, xbf);     // t1 + t1bf
    k_gemm_bf<<<dim3(512,2), 256, 0, stream>>>(xbf, Wfct, bfc, out);    // f -> d_out
    k_ln<false><<<16384, 256, 0, stream>>>(xt, out, g2, b2, yb, nullptr);// t2
    k_transpose<<<dim3(8,128,16), 256, 0, stream>>>(yb, out, 4096, 256); // final
}